// Round 1
// baseline (672.213 us; speedup 1.0000x reference)
//
#include <hip/hip_runtime.h>

typedef unsigned int u32;
typedef unsigned short u16;
typedef __bf16 bf16x8 __attribute__((ext_vector_type(8)));
typedef float f32x4 __attribute__((ext_vector_type(4)));

#define M_TOT 8192
#define N_TOT 4096
#define K_TOT 4096
#define RANK 16

__constant__ float NF4_TAB[16] = {
    -1.0f, -0.6961928009986877f, -0.5250730514526367f, -0.39491748809814453f,
    -0.28444138169288635f, -0.18477343022823334f, -0.09105003625154495f, 0.0f,
    0.07958029955625534f, 0.16093020141124725f, 0.24611230194568634f,
    0.33791524171829224f, 0.44070982933044434f, 0.5626170039176941f,
    0.7229568362236023f, 1.0f};

__device__ __forceinline__ u16 f2bf(float f) {
  u32 u = __builtin_bit_cast(u32, f);
  return (u16)((u + 0x7FFFu + ((u >> 16) & 1u)) >> 16);  // RNE
}

__device__ __forceinline__ void async_copy16(const u16* g, u16* l) {
  __builtin_amdgcn_global_load_lds(
      (const __attribute__((address_space(1))) u32*)g,
      (__attribute__((address_space(3))) u32*)l, 16, 0, 0);
}

// ---------------- x fp32 -> bf16 (8 elems/thread) ----------------
__global__ __launch_bounds__(256) void cvt_kernel(const float* __restrict__ x,
                                                  u16* __restrict__ xb) {
  int t = blockIdx.x * 256 + threadIdx.x;
  const float4* xv = (const float4*)x;
  float4 v0 = xv[2 * t], v1 = xv[2 * t + 1];
  uint4 o;
  o.x = (u32)f2bf(v0.x) | ((u32)f2bf(v0.y) << 16);
  o.y = (u32)f2bf(v0.z) | ((u32)f2bf(v0.w) << 16);
  o.z = (u32)f2bf(v1.x) | ((u32)f2bf(v1.y) << 16);
  o.w = (u32)f2bf(v1.z) | ((u32)f2bf(v1.w) << 16);
  ((uint4*)xb)[t] = o;
}

// ---------------- NF4 dequant + LoRA fold ----------------
// W_eff[o][i] = NF4[w_q[o][i]] * scales[o][i/64] + 2.0f * sum_r B[o][r]*A[r][i]
// grid (K_TOT/1024, N_TOT/16), block 256; thread handles 4 consecutive i, 16 rows o
__global__ __launch_bounds__(256) void dequant_kernel(
    const int* __restrict__ wq, const float* __restrict__ scales,
    const float* __restrict__ Aw, const float* __restrict__ Bw,
    u16* __restrict__ Wb) {
  __shared__ float Bs[16 * RANK];
  __shared__ float nf4s[16];
  int t = threadIdx.x;
  int o0 = blockIdx.y * 16;
  if (t < 16) nf4s[t] = NF4_TAB[t];
  Bs[t] = Bw[o0 * RANK + t];  // rows o0..o0+15, contiguous 256 floats
  __syncthreads();

  int i0 = blockIdx.x * 1024 + t * 4;
  float a[RANK][4];
#pragma unroll
  for (int r = 0; r < RANK; ++r) {
    float4 v = *(const float4*)(Aw + r * K_TOT + i0);
    a[r][0] = v.x; a[r][1] = v.y; a[r][2] = v.z; a[r][3] = v.w;
  }
#pragma unroll
  for (int j = 0; j < 16; ++j) {
    int o = o0 + j;
    int4 q = *(const int4*)(wq + (size_t)o * K_TOT + i0);
    float s = scales[o * (K_TOT / 64) + (i0 >> 6)];
    float d0 = 0.f, d1 = 0.f, d2 = 0.f, d3 = 0.f;
#pragma unroll
    for (int r = 0; r < RANK; ++r) {
      float b = Bs[j * RANK + r];
      d0 += b * a[r][0]; d1 += b * a[r][1];
      d2 += b * a[r][2]; d3 += b * a[r][3];
    }
    float w0 = nf4s[q.x & 15] * s + 2.0f * d0;
    float w1 = nf4s[q.y & 15] * s + 2.0f * d1;
    float w2 = nf4s[q.z & 15] * s + 2.0f * d2;
    float w3 = nf4s[q.w & 15] * s + 2.0f * d3;
    uint2 ov;
    ov.x = (u32)f2bf(w0) | ((u32)f2bf(w1) << 16);
    ov.y = (u32)f2bf(w2) | ((u32)f2bf(w3) << 16);
    *(uint2*)(Wb + (size_t)o * K_TOT + i0) = ov;
  }
}

// ---------------- bf16 GEMM: C[M,N] = A[M,K] * B[N,K]^T ----------------
// 128x128 tile, BK=32, 4 waves (2x2), each wave 64x64 via 4x4 mfma_f32_16x16x32_bf16
__global__ __launch_bounds__(256) void gemm_kernel(const u16* __restrict__ A,
                                                   const u16* __restrict__ B,
                                                   float* __restrict__ C) {
  __shared__ __align__(16) u16 As[128 * 32];  // 8 KB
  __shared__ __align__(16) u16 Bs[128 * 32];  // 8 KB

  int tid = threadIdx.x;
  int bn = blockIdx.x, bm = blockIdx.y;
  int lane = tid & 63, wave = tid >> 6;
  int wm = wave & 1, wn = wave >> 1;

  // staging: thread t loads 16B; LDS dest = lane-contiguous (global_load_lds constraint)
  int rowS = tid >> 2;          // 0..63
  int colS = (tid & 3) * 8;     // 0,8,16,24
  const u16* gA0 = A + (size_t)(bm * 128 + rowS) * K_TOT + colS;
  const u16* gA1 = A + (size_t)(bm * 128 + 64 + rowS) * K_TOT + colS;
  const u16* gB0 = B + (size_t)(bn * 128 + rowS) * K_TOT + colS;
  const u16* gB1 = B + (size_t)(bn * 128 + 64 + rowS) * K_TOT + colS;
  u16* lA0 = As + tid * 8;
  u16* lA1 = As + 2048 + tid * 8;
  u16* lB0 = Bs + tid * 8;
  u16* lB1 = Bs + 2048 + tid * 8;

  const u16* pA = As + (wm * 64 + (lane & 15)) * 32 + (lane >> 4) * 8;
  const u16* pB = Bs + (wn * 64 + (lane & 15)) * 32 + (lane >> 4) * 8;

  f32x4 acc[4][4] = {};

  for (int k0 = 0; k0 < K_TOT; k0 += 32) {
    async_copy16(gA0 + k0, lA0);
    async_copy16(gA1 + k0, lA1);
    async_copy16(gB0 + k0, lB0);
    async_copy16(gB1 + k0, lB1);
    __syncthreads();

    bf16x8 af[4], bfr[4];
#pragma unroll
    for (int i = 0; i < 4; ++i) {
      af[i] = *(const bf16x8*)(pA + i * 16 * 32);
      bfr[i] = *(const bf16x8*)(pB + i * 16 * 32);
    }
#pragma unroll
    for (int i = 0; i < 4; ++i)
#pragma unroll
      for (int j = 0; j < 4; ++j)
        acc[i][j] = __builtin_amdgcn_mfma_f32_16x16x32_bf16(af[i], bfr[j],
                                                            acc[i][j], 0, 0, 0);
    __syncthreads();
  }

  // C/D layout: col = lane&15, row = (lane>>4)*4 + reg
  int r0 = bm * 128 + wm * 64 + ((lane >> 4) << 2);
  int c0 = bn * 128 + wn * 64 + (lane & 15);
#pragma unroll
  for (int i = 0; i < 4; ++i)
#pragma unroll
    for (int j = 0; j < 4; ++j)
#pragma unroll
      for (int p = 0; p < 4; ++p)
        C[(size_t)(r0 + i * 16 + p) * N_TOT + (c0 + j * 16)] = acc[i][j][p];
}

extern "C" void kernel_launch(void* const* d_in, const int* in_sizes, int n_in,
                              void* d_out, int out_size, void* d_ws, size_t ws_size,
                              hipStream_t stream) {
  const float* x = (const float*)d_in[0];       // [4,2048,4096] fp32
  const int* wq = (const int*)d_in[1];          // [4096,4096] int32
  const float* scales = (const float*)d_in[2];  // [4096,64] fp32
  const float* Aw = (const float*)d_in[3];      // [16,4096] fp32
  const float* Bw = (const float*)d_in[4];      // [4096,16] fp32
  float* out = (float*)d_out;                   // [8192,4096] fp32

  u16* xb = (u16*)d_ws;                                   // 67,108,864 B
  u16* Wb = (u16*)((char*)d_ws + (size_t)M_TOT * K_TOT * 2);  // 33,554,432 B

  cvt_kernel<<<(M_TOT * K_TOT) / (256 * 8), 256, 0, stream>>>(x, xb);
  dequant_kernel<<<dim3(K_TOT / 1024, N_TOT / 16), 256, 0, stream>>>(wq, scales, Aw, Bw, Wb);
  gemm_kernel<<<dim3(N_TOT / 128, M_TOT / 128), 256, 0, stream>>>(xb, Wb, out);
}

// Round 2
// 588.577 us; speedup vs baseline: 1.1421x; 1.1421x over previous
//
#include <hip/hip_runtime.h>

typedef unsigned int u32;
typedef unsigned short u16;
typedef __bf16 bf16x8 __attribute__((ext_vector_type(8)));
typedef float f32x4 __attribute__((ext_vector_type(4)));

#define M_TOT 8192
#define N_TOT 4096
#define K_TOT 4096
#define RANK 16

__constant__ float NF4_TAB[16] = {
    -1.0f, -0.6961928009986877f, -0.5250730514526367f, -0.39491748809814453f,
    -0.28444138169288635f, -0.18477343022823334f, -0.09105003625154495f, 0.0f,
    0.07958029955625534f, 0.16093020141124725f, 0.24611230194568634f,
    0.33791524171829224f, 0.44070982933044434f, 0.5626170039176941f,
    0.7229568362236023f, 1.0f};

__device__ __forceinline__ u16 f2bf(float f) {
  u32 u = __builtin_bit_cast(u32, f);
  return (u16)((u + 0x7FFFu + ((u >> 16) & 1u)) >> 16);  // RNE
}

__device__ __forceinline__ void async_copy16(const u16* g, u16* l) {
  __builtin_amdgcn_global_load_lds(
      (const __attribute__((address_space(1))) u32*)g,
      (__attribute__((address_space(3))) u32*)l, 16, 0, 0);
}

// ---------------- x fp32 -> bf16 (8 elems/thread) ----------------
__global__ __launch_bounds__(256) void cvt_kernel(const float* __restrict__ x,
                                                  u16* __restrict__ xb) {
  int t = blockIdx.x * 256 + threadIdx.x;
  const float4* xv = (const float4*)x;
  float4 v0 = xv[2 * t], v1 = xv[2 * t + 1];
  uint4 o;
  o.x = (u32)f2bf(v0.x) | ((u32)f2bf(v0.y) << 16);
  o.y = (u32)f2bf(v0.z) | ((u32)f2bf(v0.w) << 16);
  o.z = (u32)f2bf(v1.x) | ((u32)f2bf(v1.y) << 16);
  o.w = (u32)f2bf(v1.z) | ((u32)f2bf(v1.w) << 16);
  ((uint4*)xb)[t] = o;
}

// ---------------- NF4 dequant + LoRA fold ----------------
// W_eff[o][i] = NF4[w_q[o][i]] * scales[o][i/64] + 2.0f * sum_r B[o][r]*A[r][i]
// NF4 lookup via ds_bpermute crossbar broadcast (no LDS bank serialization).
__global__ __launch_bounds__(256) void dequant_kernel(
    const int* __restrict__ wq, const float* __restrict__ scales,
    const float* __restrict__ Aw, const float* __restrict__ Bw,
    u16* __restrict__ Wb) {
  __shared__ float Bs[16 * RANK];
  int t = threadIdx.x;
  int o0 = blockIdx.y * 16;
  int tabi = __builtin_bit_cast(int, NF4_TAB[t & 15]);  // lanes 0-15 hold codebook
  Bs[t] = Bw[o0 * RANK + t];
  __syncthreads();

  int i0 = blockIdx.x * 1024 + t * 4;
  float a[RANK][4];
#pragma unroll
  for (int r = 0; r < RANK; ++r) {
    float4 v = *(const float4*)(Aw + r * K_TOT + i0);
    a[r][0] = v.x; a[r][1] = v.y; a[r][2] = v.z; a[r][3] = v.w;
  }
#pragma unroll
  for (int j = 0; j < 16; ++j) {
    int o = o0 + j;
    int4 q = *(const int4*)(wq + (size_t)o * K_TOT + i0);
    float s = scales[o * (K_TOT / 64) + (i0 >> 6)];
    float d0 = 0.f, d1 = 0.f, d2 = 0.f, d3 = 0.f;
#pragma unroll
    for (int r = 0; r < RANK; ++r) {
      float b = Bs[j * RANK + r];
      d0 += b * a[r][0]; d1 += b * a[r][1];
      d2 += b * a[r][2]; d3 += b * a[r][3];
    }
    float t0 = __builtin_bit_cast(float, __builtin_amdgcn_ds_bpermute((q.x & 15) << 2, tabi));
    float t1 = __builtin_bit_cast(float, __builtin_amdgcn_ds_bpermute((q.y & 15) << 2, tabi));
    float t2 = __builtin_bit_cast(float, __builtin_amdgcn_ds_bpermute((q.z & 15) << 2, tabi));
    float t3 = __builtin_bit_cast(float, __builtin_amdgcn_ds_bpermute((q.w & 15) << 2, tabi));
    float w0 = t0 * s + 2.0f * d0;
    float w1 = t1 * s + 2.0f * d1;
    float w2 = t2 * s + 2.0f * d2;
    float w3 = t3 * s + 2.0f * d3;
    uint2 ov;
    ov.x = (u32)f2bf(w0) | ((u32)f2bf(w1) << 16);
    ov.y = (u32)f2bf(w2) | ((u32)f2bf(w3) << 16);
    *(uint2*)(Wb + (size_t)o * K_TOT + i0) = ov;
  }
}

// ---------------- bf16 GEMM: C[M,N] = A[M,K] * B[N,K]^T ----------------
// 128x128 tile, BK=64, XOR-swizzled LDS (granule g of row r stored at g^(r&7)).
// 4 waves (2x2), each wave 64x64 via 4x4x2 mfma_f32_16x16x32_bf16 (32 MFMA/barrier).
__global__ __launch_bounds__(256) void gemm_kernel(const u16* __restrict__ A,
                                                   const u16* __restrict__ B,
                                                   float* __restrict__ C) {
  __shared__ __align__(16) u16 As[128 * 64];  // 16 KB
  __shared__ __align__(16) u16 Bs[128 * 64];  // 16 KB

  int tid = threadIdx.x;
  int bn = blockIdx.x, bm = blockIdx.y;
  int lane = tid & 63, wave = tid >> 6;
  int wm = wave & 1, wn = wave >> 1;

  // Staging: each copy instr covers 8 rows x 8 granules (16B each).
  // Lane l -> storage (row rb+(l>>3), granule l&7); source granule = (l&7)^(l>>3)
  // (since r&7 == l>>3 when rb % 8 == 0). Each 8-lane group reads a full
  // permuted 128B row segment -> coalesced.
  int srow = lane >> 3;
  int sg = (lane & 7) ^ srow;
  const u16 *gA[4], *gB[4];
  u16 *lA[4], *lB[4];
#pragma unroll
  for (int t = 0; t < 4; ++t) {
    int rb = (wave * 4 + t) * 8;
    gA[t] = A + (size_t)(bm * 128 + rb + srow) * K_TOT + sg * 8;
    gB[t] = B + (size_t)(bn * 128 + rb + srow) * K_TOT + sg * 8;
    lA[t] = As + rb * 64 + lane * 8;
    lB[t] = Bs + rb * 64 + lane * 8;
  }

  // Fragment reads: row r = wm*64 + i*16 + m, source granule g = kk*4+q,
  // storage offset = r*64 + ((g^(r&7))<<3); r&7 == m&7.
  int m = lane & 15, q = lane >> 4;
  int x7 = m & 7;
  const u16* pA = As + (wm * 64 + m) * 64;
  const u16* pB = Bs + (wn * 64 + m) * 64;
  int off0 = (q ^ x7) << 3;
  int off1 = ((q + 4) ^ x7) << 3;

  f32x4 acc[4][4] = {};

  for (int k0 = 0; k0 < K_TOT; k0 += 64) {
#pragma unroll
    for (int t = 0; t < 4; ++t) {
      async_copy16(gA[t] + k0, lA[t]);
      async_copy16(gB[t] + k0, lB[t]);
    }
    __syncthreads();

#pragma unroll
    for (int kk = 0; kk < 2; ++kk) {
      int off = kk ? off1 : off0;
      bf16x8 af[4], bfr[4];
#pragma unroll
      for (int i = 0; i < 4; ++i) {
        af[i] = *(const bf16x8*)(pA + i * 16 * 64 + off);
        bfr[i] = *(const bf16x8*)(pB + i * 16 * 64 + off);
      }
#pragma unroll
      for (int i = 0; i < 4; ++i)
#pragma unroll
        for (int j = 0; j < 4; ++j)
          acc[i][j] = __builtin_amdgcn_mfma_f32_16x16x32_bf16(af[i], bfr[j],
                                                              acc[i][j], 0, 0, 0);
    }
    __syncthreads();
  }

  // C/D layout: col = lane&15, row = (lane>>4)*4 + reg
  int r0 = bm * 128 + wm * 64 + (q << 2);
  int c0 = bn * 128 + wn * 64 + m;
#pragma unroll
  for (int i = 0; i < 4; ++i)
#pragma unroll
    for (int j = 0; j < 4; ++j)
#pragma unroll
      for (int p = 0; p < 4; ++p)
        C[(size_t)(r0 + i * 16 + p) * N_TOT + (c0 + j * 16)] = acc[i][j][p];
}

extern "C" void kernel_launch(void* const* d_in, const int* in_sizes, int n_in,
                              void* d_out, int out_size, void* d_ws, size_t ws_size,
                              hipStream_t stream) {
  const float* x = (const float*)d_in[0];       // [4,2048,4096] fp32
  const int* wq = (const int*)d_in[1];          // [4096,4096] int32
  const float* scales = (const float*)d_in[2];  // [4096,64] fp32
  const float* Aw = (const float*)d_in[3];      // [16,4096] fp32
  const float* Bw = (const float*)d_in[4];      // [4096,16] fp32
  float* out = (float*)d_out;                   // [8192,4096] fp32

  u16* xb = (u16*)d_ws;                                       // 67,108,864 B
  u16* Wb = (u16*)((char*)d_ws + (size_t)M_TOT * K_TOT * 2);  // 33,554,432 B

  cvt_kernel<<<(M_TOT * K_TOT) / (256 * 8), 256, 0, stream>>>(x, xb);
  dequant_kernel<<<dim3(K_TOT / 1024, N_TOT / 16), 256, 0, stream>>>(wq, scales, Aw, Bw, Wb);
  gemm_kernel<<<dim3(N_TOT / 128, M_TOT / 128), 256, 0, stream>>>(xb, Wb, out);
}